// Round 4
// baseline (979.304 us; speedup 1.0000x reference)
//
#include <hip/hip_runtime.h>
#include <hip/hip_bf16.h>

#define BATCH 1024
#define F_IN 256
#define N_D 64
#define N_A 64
#define VBS 128
#define N_STEPS 3
#define FO 128
#define D_CAT 512
#define AD 256
#define GAMMA_C 1.3f
#define BN_EPS_C 1e-5f
#define SQRT_HALF_C 0.70710678118654752440f

// ---- input loader: f32 or bf16 decided at runtime by detector flag --------
__device__ __forceinline__ float ldin(const void* p, size_t i, int isbf){
  if (isbf) return __bfloat162float(((const __hip_bfloat16*)p)[i]);
  return ((const float*)p)[i];
}

// ---- wave (64-lane) butterfly reductions ----------------------------------
__device__ __forceinline__ float wsum(float v){
#pragma unroll
  for (int o = 32; o > 0; o >>= 1) v += __shfl_xor(v, o);
  return v;
}
__device__ __forceinline__ float wmaxr(float v){
#pragma unroll
  for (int o = 32; o > 0; o >>= 1) v = fmaxf(v, __shfl_xor(v, o));
  return v;
}
__device__ __forceinline__ float wminr(float v){
#pragma unroll
  for (int o = 32; o > 0; o >>= 1) v = fminf(v, __shfl_xor(v, o));
  return v;
}
__device__ __forceinline__ float block_sum(float v, float* sb){
  int t = threadIdx.x;
  sb[t] = v; __syncthreads();
#pragma unroll
  for (int s = 128; s > 0; s >>= 1){
    if (t < s) sb[t] += sb[t + s];
    __syncthreads();
  }
  float r = sb[0]; __syncthreads();
  return r;
}

// ---- dtype detector --------------------------------------------------------
__global__ void detect_k(const unsigned short* __restrict__ u, float* __restrict__ flag){
  __shared__ int cnt;
  if (threadIdx.x == 0) cnt = 0;
  __syncthreads();
  int c = 0;
  for (int j = 0; j < 16; ++j){
    unsigned short v = u[(size_t)(threadIdx.x * 16 + j) * 2];
    int e = (v >> 7) & 0xFF;
    if (e >= 118 && e <= 134) c++;
  }
  atomicAdd(&cnt, c);
  __syncthreads();
  if (threadIdx.x == 0) flag[0] = (cnt > 2048) ? 1.0f : 0.0f;
}

// ---- full-batch BN stats ---------------------------------------------------
__global__ void bnstats_k(const void* __restrict__ x, float* __restrict__ mean,
                          float* __restrict__ istd, const float* __restrict__ flg){
  __shared__ float sb[256];
  const int isbf = flg[0] != 0.0f;
  int f = blockIdx.x, t = threadIdx.x;
  float s = 0.f, ss = 0.f;
  for (int r = t; r < BATCH; r += 256){
    float v = ldin(x, (size_t)r * F_IN + f, isbf);
    s += v; ss += v * v;
  }
  s  = block_sum(s, sb);
  ss = block_sum(ss, sb);
  if (t == 0){
    float m = s * (1.f / BATCH);
    mean[f] = m;
    istd[f] = rsqrtf(ss * (1.f / BATCH) - m * m + BN_EPS_C);
  }
}

// ---- xn + bemv->f32 --------------------------------------------------------
__global__ void xnbemv_k(const void* __restrict__ x, const float* __restrict__ mean,
                         const float* __restrict__ istd, const void* __restrict__ bw,
                         const void* __restrict__ bb, const void* __restrict__ bemv,
                         float* __restrict__ xn, float* __restrict__ bemvf,
                         const float* __restrict__ flg){
  const int isbf = flg[0] != 0.0f;
  int idx = blockIdx.x * 256 + threadIdx.x;
  int f = idx & (F_IN - 1);
  xn[idx] = (ldin(x, idx, isbf) - mean[f]) * istd[f] * ldin(bw, f, isbf) + ldin(bb, f, isbf);
  bemvf[idx] = ldin(bemv, idx, isbf);
}

// ---- batched weight transpose: Wt[k][c] = W[c][k]; all 11 matrices --------
__global__ __launch_bounds__(256)
void transpose_k(const void* __restrict__ ifc0, const void* __restrict__ ifc1,
                 const void* __restrict__ sfc0, const void* __restrict__ sfc1,
                 const void* __restrict__ afc, float* __restrict__ wt,
                 const float* __restrict__ flg){
  const int isbf = flg[0] != 0.0f;
  int z = blockIdx.z;
  const void* src; size_t soff, doff; int K;
  if (z == 0){ src = ifc0; soff = 0; doff = 0; K = 512; }
  else if (z == 1){ src = ifc1; soff = 0; doff = 131072; K = 128; }
  else if (z < 5){ int s = z-2; src = sfc0; soff = (size_t)s*131072; doff = 163840 + (size_t)s*131072; K = 512; }
  else if (z < 8){ int s = z-5; src = sfc1; soff = (size_t)s*32768;  doff = 557056 + (size_t)s*32768;  K = 128; }
  else          { int s = z-8; src = afc;  soff = (size_t)s*16384;  doff = 655360 + (size_t)s*16384;  K = 64;  }
  int kt = blockIdx.x * 32;
  if (kt >= K) return;
  int ct = blockIdx.y * 32;
  __shared__ float tile[32][33];
  int tx = threadIdx.x & 31, ty = threadIdx.x >> 5;
#pragma unroll
  for (int i = 0; i < 4; ++i){
    int c = ct + ty*4 + i;
    tile[ty*4 + i][tx] = ldin(src, soff + (size_t)c*K + kt + tx, isbf);
  }
  __syncthreads();
#pragma unroll
  for (int i = 0; i < 4; ++i){
    int k = kt + ty*4 + i;
    wt[doff + (size_t)k*256 + ct + tx] = tile[tx][ty*4 + i];
  }
}

// ---- col-per-thread GEMM: C(1024x256) = [A1|A2](1024xK) @ Wt(Kx256) -------
// thread t = output col t; R rows per block; A accessed uniformly (scalar).
template<int R>
__global__ __launch_bounds__(256)
void gemmT_k(const float* __restrict__ A1, const float* __restrict__ A2, int split,
             const float* __restrict__ Wt, float* __restrict__ C, int K){
  const int r0 = blockIdx.x * R;
  const int t = threadIdx.x;
  float acc[R];
#pragma unroll
  for (int r = 0; r < R; ++r) acc[r] = 0.f;
#pragma unroll 4
  for (int k = 0; k < K; k += 4){
    float4 a[R];
#pragma unroll
    for (int r = 0; r < R; ++r){
      int gr = r0 + r;
      a[r] = (k < split) ? *(const float4*)(A1 + (size_t)gr*split + k)
                         : *(const float4*)(A2 + (size_t)gr*(K - split) + (k - split));
    }
    const float* wrow = Wt + (size_t)k*256 + t;
#pragma unroll
    for (int j = 0; j < 4; ++j){
      float wv = wrow[(size_t)j*256];
#pragma unroll
      for (int r = 0; r < R; ++r){
        float av = (j == 0) ? a[r].x : (j == 1) ? a[r].y : (j == 2) ? a[r].z : a[r].w;
        acc[r] += av * wv;
      }
    }
  }
#pragma unroll
  for (int r = 0; r < R; ++r) C[(size_t)(r0 + r)*256 + t] = acc[r];
}

// ---- ghost-BN stats -> per-(group,col) affine -----------------------------
__global__ __launch_bounds__(256)
void gstats_k(const float* __restrict__ H, const void* __restrict__ w,
              const void* __restrict__ b, size_t off, float* __restrict__ sa,
              float* __restrict__ sb, const float* __restrict__ flg){
  __shared__ float ps[8][32], pss[8][32];
  const int isbf = flg[0] != 0.0f;
  int c0 = blockIdx.x * 32, g = blockIdx.y;
  int tx = threadIdx.x & 31, q = threadIdx.x >> 5;
  const float* Hp = H + ((size_t)g*128 + q*16) * 256 + c0 + tx;
  float s = 0.f, ss = 0.f;
#pragma unroll
  for (int i = 0; i < 16; ++i){ float v = Hp[(size_t)i*256]; s += v; ss += v*v; }
  ps[q][tx] = s; pss[q][tx] = ss;
  __syncthreads();
  if (threadIdx.x < 32){
    int t = threadIdx.x, col = c0 + t;
    float S = 0.f, SS = 0.f;
#pragma unroll
    for (int qq = 0; qq < 8; ++qq){ S += ps[qq][t]; SS += pss[qq][t]; }
    float m = S * (1.f/128), is = rsqrtf(SS * (1.f/128) - m*m + BN_EPS_C);
    float wv = ldin(w, off + col, isbf), bv = ldin(b, off + col, isbf);
    float A = is * wv;
    sa[g*256 + col] = A;
    sb[g*256 + col] = bv - m * A;
  }
}

// ---- fused sparsemax + prior + loss + sparse xm GEMM ----------------------
__global__ __launch_bounds__(256)
void spmaxxm_k(const float* __restrict__ H, const float* __restrict__ sa,
               const float* __restrict__ sb, float* __restrict__ prior,
               const float* __restrict__ xn, const void* __restrict__ gmat,
               float* __restrict__ xm, float* __restrict__ lrow,
               int first, const float* __restrict__ flg){
  __shared__ __align__(16) float tabs[4][256];
  __shared__ unsigned int msk[4][2];
  const int isbf = flg[0] != 0.0f;
  int lane = threadIdx.x & 63, wv = threadIdx.x >> 6;
  int b0 = blockIdx.x * 4;
  int b = b0 + wv, g = b >> 7;
  size_t rb = (size_t)b * 256;
  int j0 = lane * 4;
  float4 h4 = *(const float4*)(H + rb + j0);
  float4 A4 = *(const float4*)(sa + (size_t)g*256 + j0);
  float4 B4 = *(const float4*)(sb + (size_t)g*256 + j0);
  float pr[4];
  if (first){ pr[0] = pr[1] = pr[2] = pr[3] = 1.f; }
  else { float4 p4 = *(const float4*)(prior + rb + j0); pr[0]=p4.x; pr[1]=p4.y; pr[2]=p4.z; pr[3]=p4.w; }
  float z[4];
  z[0] = (h4.x*A4.x + B4.x) * pr[0];
  z[1] = (h4.y*A4.y + B4.y) * pr[1];
  z[2] = (h4.z*A4.z + B4.z) * pr[2];
  z[3] = (h4.w*A4.w + B4.w) * pr[3];
  float zm = wmaxr(fmaxf(fmaxf(z[0], z[1]), fmaxf(z[2], z[3])));
  float lo = zm - 1.f, hi = zm;
#pragma unroll 1
  for (int it = 0; it < 30; ++it){
    float mid = 0.5f * (lo + hi);
    float s = 0.f;
#pragma unroll
    for (int e = 0; e < 4; ++e){ float d = z[e] - mid; s += d > 0.f ? d : 0.f; }
    s = wsum(s);
    if (s >= 1.f) lo = mid; else hi = mid;
  }
  float tau = 0.5f * (lo + hi);
  float p[4], ls = 0.f;
#pragma unroll
  for (int e = 0; e < 4; ++e){
    p[e] = z[e] - tau; p[e] = p[e] > 0.f ? p[e] : 0.f;
    ls += p[e] * __logf(p[e] + 1e-15f);
  }
  *(float4*)&tabs[wv][j0] = make_float4(p[0], p[1], p[2], p[3]);
  *(float4*)(prior + rb + j0) = make_float4(pr[0]*(GAMMA_C - p[0]), pr[1]*(GAMMA_C - p[1]),
                                            pr[2]*(GAMMA_C - p[2]), pr[3]*(GAMMA_C - p[3]));
  ls = wsum(ls);
  if (lane == 0) lrow[b] = ls;
  bool nz = (p[0] > 0.f) | (p[1] > 0.f) | (p[2] > 0.f) | (p[3] > 0.f);
  unsigned long long bm = __ballot(nz);
  if (lane == 0){ msk[wv][0] = (unsigned int)bm; msk[wv][1] = (unsigned int)(bm >> 32); }
  __syncthreads();
  // phase 2: thread t = col t; sparse chunk skip via uniform masks
  int t = threadIdx.x;
  unsigned long long M0 = msk[0][0] | ((unsigned long long)msk[0][1] << 32);
  unsigned long long M1 = msk[1][0] | ((unsigned long long)msk[1][1] << 32);
  unsigned long long M2 = msk[2][0] | ((unsigned long long)msk[2][1] << 32);
  unsigned long long M3 = msk[3][0] | ((unsigned long long)msk[3][1] << 32);
  float a0 = 0.f, a1 = 0.f, a2 = 0.f, a3 = 0.f;
#pragma unroll 1
  for (int c = 0; c < 64; ++c){
    int r0a = (int)((M0 >> c) & 1), r1a = (int)((M1 >> c) & 1);
    int r2a = (int)((M2 >> c) & 1), r3a = (int)((M3 >> c) & 1);
    if (r0a | r1a | r2a | r3a){
      int k = c * 4;
      float g0 = ldin(gmat, (size_t)(k+0)*256 + t, isbf);
      float g1 = ldin(gmat, (size_t)(k+1)*256 + t, isbf);
      float g2 = ldin(gmat, (size_t)(k+2)*256 + t, isbf);
      float g3 = ldin(gmat, (size_t)(k+3)*256 + t, isbf);
      if (r0a){ float4 tv = *(float4*)&tabs[0][k]; a0 += tv.x*g0 + tv.y*g1 + tv.z*g2 + tv.w*g3; }
      if (r1a){ float4 tv = *(float4*)&tabs[1][k]; a1 += tv.x*g0 + tv.y*g1 + tv.z*g2 + tv.w*g3; }
      if (r2a){ float4 tv = *(float4*)&tabs[2][k]; a2 += tv.x*g0 + tv.y*g1 + tv.z*g2 + tv.w*g3; }
      if (r3a){ float4 tv = *(float4*)&tabs[3][k]; a3 += tv.x*g0 + tv.y*g1 + tv.z*g2 + tv.w*g3; }
    }
  }
  xm[(size_t)(b0+0)*256 + t] = a0 * xn[(size_t)(b0+0)*256 + t];
  xm[(size_t)(b0+1)*256 + t] = a1 * xn[(size_t)(b0+1)*256 + t];
  xm[(size_t)(b0+2)*256 + t] = a2 * xn[(size_t)(b0+2)*256 + t];
  xm[(size_t)(b0+3)*256 + t] = a3 * xn[(size_t)(b0+3)*256 + t];
}

// ---- tiled self-attention: block = 64 rows x 256 cols, exp computed once --
__global__ __launch_bounds__(256)
void attn2_k(const float* __restrict__ xm, float* __restrict__ y,
             const void* __restrict__ in_w, const void* __restrict__ in_b,
             const void* __restrict__ out_w, const void* __restrict__ out_b,
             int s, float* __restrict__ amap, const float* __restrict__ flg){
  __shared__ __align__(16) float ql[256], kl[256], vl[256];
  __shared__ float Zp[64][17], Yp[64][17];
  __shared__ __align__(16) float rzl[64];
  __shared__ float r1[4], r2[4];
  const int isbf = flg[0] != 0.0f;
  int rt = blockIdx.x, b = blockIdx.y;
  int t = threadIdx.x, tx = t & 15, ty = t >> 4;
  float w0 = ldin(in_w, s*3+0, isbf), w1 = ldin(in_w, s*3+1, isbf), w2 = ldin(in_w, s*3+2, isbf);
  float b0 = ldin(in_b, s*3+0, isbf), b1 = ldin(in_b, s*3+1, isbf), b2 = ldin(in_b, s*3+2, isbf);
  float ow = ldin(out_w, s, isbf), ob = ldin(out_b, s, isbf);
  float xv = xm[(size_t)b*256 + t];
  float q = xv*w0 + b0, k = xv*w1 + b1, v = xv*w2 + b2;
  ql[t] = q; kl[t] = k; vl[t] = v;
  int lane = t & 63, wv = t >> 6;
  float km = wmaxr(k), kn = wminr(k);
  if (lane == 0){ r1[wv] = km; r2[wv] = kn; }
  __syncthreads();
  float kmax = fmaxf(fmaxf(r1[0], r1[1]), fmaxf(r1[2], r1[3]));
  float kmin = fminf(fminf(r2[0], r2[1]), fminf(r2[2], r2[3]));
  int i0 = rt*64 + ty*4;
  float4 q4 = *(const float4*)&ql[i0];
  float m4[4], qa[4];
  qa[0] = q4.x; qa[1] = q4.y; qa[2] = q4.z; qa[3] = q4.w;
#pragma unroll
  for (int rr = 0; rr < 4; ++rr) m4[rr] = (qa[rr] >= 0.f) ? qa[rr]*kmax : qa[rr]*kmin;
  float E[4][16];
  float Zs[4] = {0.f, 0.f, 0.f, 0.f}, Ys[4] = {0.f, 0.f, 0.f, 0.f};
#pragma unroll
  for (int j = 0; j < 16; ++j){
    int c = tx + j*16;
    float kc = kl[c], vc = vl[c];
#pragma unroll
    for (int rr = 0; rr < 4; ++rr){
      float e = __expf(qa[rr]*kc - m4[rr]);
      E[rr][j] = e;
      Zs[rr] += e; Ys[rr] += e*vc;
    }
  }
#pragma unroll
  for (int rr = 0; rr < 4; ++rr){
    Zp[ty*4 + rr][tx] = Zs[rr];
    Yp[ty*4 + rr][tx] = Ys[rr];
  }
  __syncthreads();
  if (t < 64){
    float Z = 0.f, Y = 0.f;
#pragma unroll
    for (int i = 0; i < 16; ++i){ Z += Zp[t][i]; Y += Yp[t][i]; }
    float rz = 1.f / Z;
    rzl[t] = rz;
    y[(size_t)b*256 + rt*64 + t] = Y*rz*ow + ob;
  }
  __syncthreads();
  float4 rz4 = *(const float4*)&rzl[ty*4];
  float rza[4] = {rz4.x, rz4.y, rz4.z, rz4.w};
  size_t base = ((size_t)s*BATCH + b) * 65536;
#pragma unroll
  for (int rr = 0; rr < 4; ++rr){
    size_t rowb = base + (size_t)(i0 + rr)*256 + tx;
#pragma unroll
    for (int j = 0; j < 16; ++j){
      __builtin_nontemporal_store(E[rr][j] * rza[rr], amap + rowb + (size_t)j*16);
    }
  }
}

// ---- ghost-BN + GLU (+ optional combine epilogue) -------------------------
template<int MODE>
__global__ __launch_bounds__(256)
void gbnglu_k(const float* __restrict__ H, const void* __restrict__ w,
              const void* __restrict__ b, size_t off, const float* __restrict__ G0,
              float* __restrict__ Gout, float* __restrict__ att,
              float* __restrict__ steps_out, const float* __restrict__ flg){
  __shared__ float ps[4][64], pss[4][64];
  __shared__ float sA[64], sB[64];
  const int isbf = flg[0] != 0.0f;
  int c0 = blockIdx.x * 32, g = blockIdx.y;
  int t = threadIdx.x;
  int tx = t & 63, q = t >> 6;
  int cc = tx & 31, half = tx >> 5;
  int col = c0 + cc + half*128;
  const float* Hp = H + ((size_t)g*128 + q*32) * 256 + col;
  float s = 0.f, ss = 0.f;
#pragma unroll
  for (int i = 0; i < 32; ++i){ float v = Hp[(size_t)i*256]; s += v; ss += v*v; }
  ps[q][tx] = s; pss[q][tx] = ss;
  __syncthreads();
  if (t < 64){
    float S  = ps[0][t] + ps[1][t] + ps[2][t] + ps[3][t];
    float SS = pss[0][t] + pss[1][t] + pss[2][t] + pss[3][t];
    float m  = S * (1.f/128), is = rsqrtf(SS * (1.f/128) - m*m + BN_EPS_C);
    int colT = c0 + (t & 31) + (t >> 5)*128;
    float wv = ldin(w, off + colT, isbf), bv = ldin(b, off + colT, isbf);
    float A = is * wv;
    sA[t] = A; sB[t] = bv - m*A;
  }
  __syncthreads();
  int oc = t & 31;
  int rbase = (t >> 5) * 16;
#pragma unroll
  for (int i = 0; i < 16; ++i){
    int r = g*128 + rbase + i;
    float h0 = H[(size_t)r*256 + c0 + oc];
    float h1 = H[(size_t)r*256 + c0 + oc + 128];
    float n0 = h0 * sA[oc]    + sB[oc];
    float n1 = h1 * sA[32+oc] + sB[32+oc];
    float gl = n0 / (1.f + __expf(-n1));
    int j = c0 + oc;
    if constexpr (MODE == 0){
      Gout[(size_t)r*128 + j] = gl;
    } else {
      float f = (G0[(size_t)r*128 + j] + gl) * SQRT_HALF_C;
      if (j < 64){
        if (steps_out) steps_out[(size_t)r*64 + j] = f > 0.f ? f : 0.01f*f;
      } else {
        att[(size_t)r*64 + (j - 64)] = f;
      }
    }
  }
}

// ---- final m_loss ----------------------------------------------------------
__global__ void mloss_k(const float* __restrict__ lrow, float* __restrict__ outp){
  __shared__ float sb[256];
  int t = threadIdx.x;
  float s = 0.f;
  for (int i = t; i < N_STEPS*BATCH; i += 256) s += lrow[i];
  s = block_sum(s, sb);
  if (t == 0) outp[0] = s * (1.f/(N_STEPS*(float)BATCH));
}

extern "C" void kernel_launch(void* const* d_in, const int* in_sizes, int n_in,
                              void* d_out, int out_size, void* d_ws, size_t ws_size,
                              hipStream_t stream){
  const void* x         = d_in[0];
  const void* bemv      = d_in[1];
  const void* gmat      = d_in[2];
  const void* bn_w      = d_in[3];
  const void* bn_b      = d_in[4];
  const void* init_fc0  = d_in[5];
  const void* init_bnw0 = d_in[6];
  const void* init_bnb0 = d_in[7];
  const void* init_fc1  = d_in[8];
  const void* init_bnw1 = d_in[9];
  const void* init_bnb1 = d_in[10];
  const void* step_fc0  = d_in[11];
  const void* step_bnw0 = d_in[12];
  const void* step_bnb0 = d_in[13];
  const void* step_fc1  = d_in[14];
  const void* step_bnw1 = d_in[15];
  const void* step_bnb1 = d_in[16];
  const void* att_fc    = d_in[17];
  const void* att_bnw   = d_in[18];
  const void* att_bnb   = d_in[19];
  const void* sa_in_w   = d_in[20];
  const void* sa_in_b   = d_in[21];
  const void* sa_out_w  = d_in[22];
  const void* sa_out_b  = d_in[23];

  float* out       = (float*)d_out;
  float* steps_out = out;                                  // 3*1024*64 f32
  float* mloss_out = out + (size_t)N_STEPS*BATCH*N_D;      // 1 f32
  float* amaps     = mloss_out + 1;                        // 3*1024*256*256 f32

  float* w     = (float*)d_ws;
  float* flag  = w;                   // 1 (pad 16)
  float* mean  = w + 16;              // 256
  float* istd  = w + 272;             // 256
  float* lrow  = w + 528;             // 3072
  float* sa    = w + 3600;            // 2048
  float* sbuf  = w + 5648;            // 2048 (-> 7696)
  float* xn    = w + 8192;            // 262144
  float* bemvf = xn    + 262144;      // 262144
  float* H     = bemvf + 262144;      // 262144
  float* G0    = H     + 262144;      // 131072
  float* att   = G0    + 131072;      // 65536
  float* xm    = att   + 65536;       // 262144
  float* y     = xm    + 262144;      // 262144
  float* prior = y     + 262144;      // 262144
  float* wt    = prior + 262144;      // 704512  (total ~2.48M f32)

  detect_k<<<1, 256, 0, stream>>>((const unsigned short*)x, flag);
  bnstats_k<<<256, 256, 0, stream>>>(x, mean, istd, flag);
  xnbemv_k<<<1024, 256, 0, stream>>>(x, mean, istd, bn_w, bn_b, bemv, xn, bemvf, flag);
  transpose_k<<<dim3(16, 8, 11), 256, 0, stream>>>(init_fc0, init_fc1, step_fc0, step_fc1, att_fc, wt, flag);

  float* wt_i0 = wt;            // 512x256
  float* wt_i1 = wt + 131072;   // 128x256
  float* wt_s0 = wt + 163840;   // 3 x 512x256
  float* wt_s1 = wt + 557056;   // 3 x 128x256
  float* wt_af = wt + 655360;   // 3 x 64x256

  dim3 gluGrid(4, 8);
  dim3 gstGrid(8, 8);

  // initial feature transformer on [xn | bemv]
  gemmT_k<4><<<256, 256, 0, stream>>>(xn, bemvf, 256, wt_i0, H, 512);
  gbnglu_k<0><<<gluGrid, 256, 0, stream>>>(H, init_bnw0, init_bnb0, 0, nullptr, G0, nullptr, nullptr, flag);
  gemmT_k<4><<<256, 256, 0, stream>>>(G0, nullptr, 128, wt_i1, H, 128);
  gbnglu_k<1><<<gluGrid, 256, 0, stream>>>(H, init_bnw1, init_bnb1, 0, G0, nullptr, att, nullptr, flag);

  for (int s = 0; s < N_STEPS; ++s){
    // a = GBN(att @ att_fc[s]^T)
    gemmT_k<4><<<256, 256, 0, stream>>>(att, nullptr, 64, wt_af + (size_t)s*16384, H, 64);
    gstats_k<<<gstGrid, 256, 0, stream>>>(H, att_bnw, att_bnb, (size_t)s*256, sa, sbuf, flag);
    // sparsemax + prior + loss + sparse xm GEMM
    spmaxxm_k<<<256, 256, 0, stream>>>(H, sa, sbuf, prior, xn, gmat, xm, lrow + s*1024, s == 0, flag);
    // tiled self-attn + amap
    attn2_k<<<dim3(4, 1024), 256, 0, stream>>>(xm, y, sa_in_w, sa_in_b, sa_out_w, sa_out_b, s, amaps, flag);
    // step feature transformer on [y | bemv]
    gemmT_k<4><<<256, 256, 0, stream>>>(y, bemvf, 256, wt_s0 + (size_t)s*131072, H, 512);
    gbnglu_k<0><<<gluGrid, 256, 0, stream>>>(H, step_bnw0, step_bnb0, (size_t)s*256, nullptr, G0, nullptr, nullptr, flag);
    gemmT_k<4><<<256, 256, 0, stream>>>(G0, nullptr, 128, wt_s1 + (size_t)s*32768, H, 128);
    gbnglu_k<1><<<gluGrid, 256, 0, stream>>>(H, step_bnw1, step_bnb1, (size_t)s*256, G0, nullptr, att,
                                             steps_out + (size_t)s*BATCH*N_D, flag);
  }
  mloss_k<<<1, 256, 0, stream>>>(lrow, mloss_out);
}

// Round 5
// 448.858 us; speedup vs baseline: 2.1818x; 2.1818x over previous
//
#include <hip/hip_runtime.h>
#include <hip/hip_bf16.h>

#define BATCH 1024
#define F_IN 256
#define N_D 64
#define N_A 64
#define VBS 128
#define N_STEPS 3
#define FO 128
#define D_CAT 512
#define AD 256
#define GAMMA_C 1.3f
#define BN_EPS_C 1e-5f
#define SQRT_HALF_C 0.70710678118654752440f

// ---- input loader: f32 or bf16 decided at runtime by detector flag --------
__device__ __forceinline__ float ldin(const void* p, size_t i, int isbf){
  if (isbf) return __bfloat162float(((const __hip_bfloat16*)p)[i]);
  return ((const float*)p)[i];
}
__device__ __forceinline__ float4 ld4(const void* p, size_t i, int isbf){
  if (!isbf) return *(const float4*)((const float*)p + i);
  const __hip_bfloat16* q = (const __hip_bfloat16*)p + i;
  return make_float4(__bfloat162float(q[0]), __bfloat162float(q[1]),
                     __bfloat162float(q[2]), __bfloat162float(q[3]));
}

// ---- wave (64-lane) butterfly reductions: result in ALL lanes -------------
__device__ __forceinline__ float wsum(float v){
#pragma unroll
  for (int o = 32; o > 0; o >>= 1) v += __shfl_xor(v, o);
  return v;
}
__device__ __forceinline__ float wmaxr(float v){
#pragma unroll
  for (int o = 32; o > 0; o >>= 1) v = fmaxf(v, __shfl_xor(v, o));
  return v;
}
__device__ __forceinline__ float wminr(float v){
#pragma unroll
  for (int o = 32; o > 0; o >>= 1) v = fminf(v, __shfl_xor(v, o));
  return v;
}
__device__ __forceinline__ float block_sum(float v, float* sb){
  int t = threadIdx.x;
  sb[t] = v; __syncthreads();
#pragma unroll
  for (int s = 128; s > 0; s >>= 1){
    if (t < s) sb[t] += sb[t + s];
    __syncthreads();
  }
  float r = sb[0]; __syncthreads();
  return r;
}

// ---- dtype detector (even uint16s: f32 mantissa=uniform, bf16=narrow exp) -
__global__ void detect_k(const unsigned short* __restrict__ u, float* __restrict__ flag){
  __shared__ int cnt;
  if (threadIdx.x == 0) cnt = 0;
  __syncthreads();
  int c = 0;
  for (int j = 0; j < 16; ++j){
    unsigned short v = u[(size_t)(threadIdx.x * 16 + j) * 2];
    int e = (v >> 7) & 0xFF;
    if (e >= 118 && e <= 134) c++;
  }
  atomicAdd(&cnt, c);
  __syncthreads();
  if (threadIdx.x == 0) flag[0] = (cnt > 2048) ? 1.0f : 0.0f;
}

// ---- full-batch BN stats (one block per feature) ---------------------------
__global__ void bnstats_k(const void* __restrict__ x, float* __restrict__ mean,
                          float* __restrict__ istd, const float* __restrict__ flg){
  __shared__ float sb[256];
  const int isbf = flg[0] != 0.0f;
  int f = blockIdx.x, t = threadIdx.x;
  float s = 0.f, ss = 0.f;
  for (int r = t; r < BATCH; r += 256){
    float v = ldin(x, (size_t)r * F_IN + f, isbf);
    s += v; ss += v * v;
  }
  s  = block_sum(s, sb);
  ss = block_sum(ss, sb);
  if (t == 0){
    float m = s * (1.f / BATCH);
    mean[f] = m;
    istd[f] = rsqrtf(ss * (1.f / BATCH) - m * m + BN_EPS_C);
  }
}

__global__ void xn_k(const void* __restrict__ x, const float* __restrict__ mean,
                     const float* __restrict__ istd, const void* __restrict__ bw,
                     const void* __restrict__ bb, float* __restrict__ xn,
                     const float* __restrict__ flg){
  const int isbf = flg[0] != 0.0f;
  int idx = blockIdx.x * 256 + threadIdx.x;
  int f = idx & (F_IN - 1);
  xn[idx] = (ldin(x, idx, isbf) - mean[f]) * istd[f] * ldin(bw, f, isbf) + ldin(bb, f, isbf);
}

// ---- GEMM (BT): C(1024x256) = A(1024xK) @ W^T, W (256,K) row-major --------
// A = virtual concat [A1 f32 | A2 input] split at `split` cols. BK=32,
// float4 loads, reg double-buffer, LDS [kk][r] so fragments are ds_read_b64.
__global__ __launch_bounds__(256)
void gemm_bt_k(const float* __restrict__ A1, const void* __restrict__ A2, int split,
               const void* __restrict__ W, size_t woff, float* __restrict__ C,
               int K, const float* __restrict__ flg){
  __shared__ float As[32][34];
  __shared__ float Ws[32][34];
  const int isbf = flg[0] != 0.0f;
  const int n0 = blockIdx.x * 32, m0 = blockIdx.y * 32;
  const int t = threadIdx.x;
  const int tx = t & 15, ty = t >> 4;
  const int lr = t >> 3, lk = (t & 7) * 4;
  const int nc = K >> 5;
  float a00 = 0.f, a01 = 0.f, a10 = 0.f, a11 = 0.f;

  auto lda = [&](int k0) -> float4 {
    int gk = k0 + lk, gr = m0 + lr;
    if (gk < split) return *(const float4*)(A1 + (size_t)gr * split + gk);
    return ld4(A2, (size_t)gr * (K - split) + (gk - split), isbf);
  };
  auto ldw = [&](int k0) -> float4 {
    return ld4(W, woff + (size_t)(n0 + lr) * K + k0 + lk, isbf);
  };

  float4 ra = lda(0), rw = ldw(0);
  for (int c = 0; c < nc; ++c){
    As[lk+0][lr] = ra.x; As[lk+1][lr] = ra.y; As[lk+2][lr] = ra.z; As[lk+3][lr] = ra.w;
    Ws[lk+0][lr] = rw.x; Ws[lk+1][lr] = rw.y; Ws[lk+2][lr] = rw.z; Ws[lk+3][lr] = rw.w;
    __syncthreads();
    float4 na = ra, nw = rw;
    if (c + 1 < nc){ na = lda((c+1) << 5); nw = ldw((c+1) << 5); }
#pragma unroll
    for (int kk = 0; kk < 32; ++kk){
      float2 av = *(const float2*)&As[kk][ty*2];
      float2 wv = *(const float2*)&Ws[kk][tx*2];
      a00 += av.x * wv.x; a01 += av.x * wv.y;
      a10 += av.y * wv.x; a11 += av.y * wv.y;
    }
    __syncthreads();
    ra = na; rw = nw;
  }
  int r0 = m0 + ty*2, c0 = n0 + tx*2;
  float* Cp = C + (size_t)r0 * 256 + c0;
  Cp[0] = a00; Cp[1] = a01; Cp[256] = a10; Cp[257] = a11;
}

// ---- ghost-BN stats -> per-(group,col) affine (a = istd*w, b2 = b - m*a) --
__global__ __launch_bounds__(256)
void gstats_k(const float* __restrict__ H, const void* __restrict__ w,
              const void* __restrict__ b, size_t off, float* __restrict__ sa,
              float* __restrict__ sb, const float* __restrict__ flg){
  __shared__ float ps[8][32], pss[8][32];
  const int isbf = flg[0] != 0.0f;
  int c0 = blockIdx.x * 32, g = blockIdx.y;
  int tx = threadIdx.x & 31, q = threadIdx.x >> 5;
  const float* Hp = H + ((size_t)g*128 + q*16) * 256 + c0 + tx;
  float s = 0.f, ss = 0.f;
#pragma unroll
  for (int i = 0; i < 16; ++i){ float v = Hp[(size_t)i*256]; s += v; ss += v*v; }
  ps[q][tx] = s; pss[q][tx] = ss;
  __syncthreads();
  if (threadIdx.x < 32){
    int t = threadIdx.x, col = c0 + t;
    float S = 0.f, SS = 0.f;
#pragma unroll
    for (int qq = 0; qq < 8; ++qq){ S += ps[qq][t]; SS += pss[qq][t]; }
    float m = S * (1.f/128), is = rsqrtf(SS * (1.f/128) - m*m + BN_EPS_C);
    float wv = ldin(w, off + col, isbf), bv = ldin(b, off + col, isbf);
    float A = is * wv;
    sa[g*256 + col] = A;
    sb[g*256 + col] = bv - m * A;
  }
}

// ---- sparsemax: wave-per-row, zero barriers. Fuses GBN-normalize, prior ---
__global__ __launch_bounds__(256)
void spmax_k(const float* __restrict__ H, const float* __restrict__ sa,
             const float* __restrict__ sb, float* __restrict__ prior,
             float* __restrict__ tab, float* __restrict__ lrow, int first){
  int lane = threadIdx.x & 63, wv = threadIdx.x >> 6;
  int b = blockIdx.x * 4 + wv, g = b >> 7;
  size_t rb = (size_t)b * 256;
  float z[4], pr[4];
#pragma unroll
  for (int e = 0; e < 4; ++e){
    int j = e*64 + lane;
    pr[e] = first ? 1.f : prior[rb + j];
    z[e] = (H[rb + j] * sa[g*256 + j] + sb[g*256 + j]) * pr[e];
  }
  float zm = wmaxr(fmaxf(fmaxf(z[0], z[1]), fmaxf(z[2], z[3])));
  float lo = zm - 1.f, hi = zm;
#pragma unroll 1
  for (int it = 0; it < 30; ++it){
    float mid = 0.5f * (lo + hi);
    float s = 0.f;
#pragma unroll
    for (int e = 0; e < 4; ++e){ float d = z[e] - mid; s += d > 0.f ? d : 0.f; }
    s = wsum(s);
    if (s >= 1.f) lo = mid; else hi = mid;
  }
  float tau = 0.5f * (lo + hi);
  float ls = 0.f;
#pragma unroll
  for (int e = 0; e < 4; ++e){
    int j = e*64 + lane;
    float p = z[e] - tau; p = p > 0.f ? p : 0.f;
    tab[rb + j]   = p;
    prior[rb + j] = pr[e] * (GAMMA_C - p);
    ls += p * __logf(p + 1e-15f);
  }
  ls = wsum(ls);
  if (lane == 0) lrow[b] = ls;
}

// ---- fused x_masked GEMM + 1D self-attention + amap write -----------------
__global__ __launch_bounds__(256)
void attn_k(const float* __restrict__ tab, const void* __restrict__ gmat,
            const float* __restrict__ xn, float* __restrict__ y,
            const void* __restrict__ in_w, const void* __restrict__ in_b,
            const void* __restrict__ out_w, const void* __restrict__ out_b,
            int s, float* __restrict__ amap, const float* __restrict__ flg){
  __shared__ __align__(16) float tabs[256], qs[256], ks[256], vs[256], ms[256], rz[256];
  __shared__ float r1[4], r2[4];
  const int isbf = flg[0] != 0.0f;
  int b = blockIdx.x, t = threadIdx.x;
  tabs[t] = tab[(size_t)b*256 + t];
  __syncthreads();
  // xm[t] = sum_k tab[b][k] * gmat[k][t]  (gmat 256KB, L2-resident)
  float xm = 0.f;
  if (isbf){
    const __hip_bfloat16* gm = (const __hip_bfloat16*)gmat;
#pragma unroll 8
    for (int k2 = 0; k2 < 256; ++k2) xm += tabs[k2] * __bfloat162float(gm[k2*256 + t]);
  } else {
    const float* gm = (const float*)gmat;
#pragma unroll 8
    for (int k2 = 0; k2 < 256; ++k2) xm += tabs[k2] * gm[k2*256 + t];
  }
  xm *= xn[(size_t)b*256 + t];
  float w0 = ldin(in_w, s*3+0, isbf), w1 = ldin(in_w, s*3+1, isbf), w2 = ldin(in_w, s*3+2, isbf);
  float b0 = ldin(in_b, s*3+0, isbf), b1 = ldin(in_b, s*3+1, isbf), b2 = ldin(in_b, s*3+2, isbf);
  float ow = ldin(out_w, s, isbf), ob = ldin(out_b, s, isbf);
  float q = xm*w0 + b0, k = xm*w1 + b1, v = xm*w2 + b2;
  qs[t] = q; ks[t] = k; vs[t] = v;
  int lane = t & 63, wv = t >> 6;
  float km = wmaxr(k), kn = wminr(k);
  if (lane == 0){ r1[wv] = km; r2[wv] = kn; }
  __syncthreads();
  float kmax = fmaxf(fmaxf(r1[0], r1[1]), fmaxf(r1[2], r1[3]));
  float kmin = fminf(fminf(r2[0], r2[1]), fminf(r2[2], r2[3]));
  // pass A: thread t owns row i=t; closed-form row max
  float mi = (q >= 0.f) ? q*kmax : q*kmin;
  float Z = 0.f, Y = 0.f;
#pragma unroll 8
  for (int j = 0; j < 256; j += 4){
    float4 k4 = *(const float4*)&ks[j];
    float4 v4 = *(const float4*)&vs[j];
    float e0 = __expf(q*k4.x - mi), e1 = __expf(q*k4.y - mi);
    float e2 = __expf(q*k4.z - mi), e3 = __expf(q*k4.w - mi);
    Z += (e0 + e1) + (e2 + e3);
    Y += (e0*v4.x + e1*v4.y) + (e2*v4.z + e3*v4.w);
  }
  float rzv = 1.f / Z;
  y[(size_t)b*256 + t] = Y*rzv*ow + ob;
  ms[t] = mi; rz[t] = rzv;
  __syncthreads();
  // pass B: thread t owns 2 adjacent cols x 128 rows. float2 temporal stores
  // (8B-aligned since amap base is even; 512B contiguous per wave-instr;
  //  L2 write-back merges into full lines -> no partial-line HBM writes).
  int c0 = (t & 127) * 2;
  int rh = (t >> 7) * 128;
  float k0 = ks[c0], k1 = ks[c0 + 1];
  size_t base = ((size_t)s*BATCH + b) * 65536 + c0;
#pragma unroll 8
  for (int i = 0; i < 128; i += 4){
    int r = rh + i;
    float4 q4 = *(const float4*)&qs[r];
    float4 m4 = *(const float4*)&ms[r];
    float4 s4 = *(const float4*)&rz[r];
    float e00 = __expf(q4.x*k0 - m4.x) * s4.x, e01 = __expf(q4.x*k1 - m4.x) * s4.x;
    float e10 = __expf(q4.y*k0 - m4.y) * s4.y, e11 = __expf(q4.y*k1 - m4.y) * s4.y;
    float e20 = __expf(q4.z*k0 - m4.z) * s4.z, e21 = __expf(q4.z*k1 - m4.z) * s4.z;
    float e30 = __expf(q4.w*k0 - m4.w) * s4.w, e31 = __expf(q4.w*k1 - m4.w) * s4.w;
    *(float2*)(amap + base + (size_t)(r+0)*256) = make_float2(e00, e01);
    *(float2*)(amap + base + (size_t)(r+1)*256) = make_float2(e10, e11);
    *(float2*)(amap + base + (size_t)(r+2)*256) = make_float2(e20, e21);
    *(float2*)(amap + base + (size_t)(r+3)*256) = make_float2(e30, e31);
  }
}

// ---- ghost-BN + GLU (+ optional combine epilogue) -------------------------
// grid (4 colchunks, 8 groups), 256 thr. MODE 0: write G0. MODE 1: combine
// f=(G0+glu)*sqrt_half -> steps_out (j<64, leaky) / att (j>=64).
template<int MODE>
__global__ __launch_bounds__(256)
void gbnglu_k(const float* __restrict__ H, const void* __restrict__ w,
              const void* __restrict__ b, size_t off, const float* __restrict__ G0,
              float* __restrict__ Gout, float* __restrict__ att,
              float* __restrict__ steps_out, const float* __restrict__ flg){
  __shared__ float ps[4][64], pss[4][64];
  __shared__ float sA[64], sB[64];
  const int isbf = flg[0] != 0.0f;
  int c0 = blockIdx.x * 32, g = blockIdx.y;
  int t = threadIdx.x;
  int tx = t & 63, q = t >> 6;
  int cc = tx & 31, half = tx >> 5;
  int col = c0 + cc + half*128;
  const float* Hp = H + ((size_t)g*128 + q*32) * 256 + col;
  float s = 0.f, ss = 0.f;
#pragma unroll
  for (int i = 0; i < 32; ++i){ float v = Hp[(size_t)i*256]; s += v; ss += v*v; }
  ps[q][tx] = s; pss[q][tx] = ss;
  __syncthreads();
  if (t < 64){
    float S  = ps[0][t] + ps[1][t] + ps[2][t] + ps[3][t];
    float SS = pss[0][t] + pss[1][t] + pss[2][t] + pss[3][t];
    float m  = S * (1.f/128), is = rsqrtf(SS * (1.f/128) - m*m + BN_EPS_C);
    int colT = c0 + (t & 31) + (t >> 5)*128;
    float wv = ldin(w, off + colT, isbf), bv = ldin(b, off + colT, isbf);
    float A = is * wv;
    sA[t] = A; sB[t] = bv - m*A;
  }
  __syncthreads();
  int oc = t & 31;
  int rbase = (t >> 5) * 16;
#pragma unroll
  for (int i = 0; i < 16; ++i){
    int r = g*128 + rbase + i;
    float h0 = H[(size_t)r*256 + c0 + oc];
    float h1 = H[(size_t)r*256 + c0 + oc + 128];
    float n0 = h0 * sA[oc]    + sB[oc];
    float n1 = h1 * sA[32+oc] + sB[32+oc];
    float gl = n0 / (1.f + __expf(-n1));
    int j = c0 + oc;
    if constexpr (MODE == 0){
      Gout[(size_t)r*128 + j] = gl;
    } else {
      float f = (G0[(size_t)r*128 + j] + gl) * SQRT_HALF_C;
      if (j < 64){
        if (steps_out) steps_out[(size_t)r*64 + j] = f > 0.f ? f : 0.01f*f;
      } else {
        att[(size_t)r*64 + (j - 64)] = f;
      }
    }
  }
}

// ---- final m_loss ----------------------------------------------------------
__global__ void mloss_k(const float* __restrict__ lrow, float* __restrict__ outp){
  __shared__ float sb[256];
  int t = threadIdx.x;
  float s = 0.f;
  for (int i = t; i < N_STEPS*BATCH; i += 256) s += lrow[i];
  s = block_sum(s, sb);
  if (t == 0) outp[0] = s * (1.f/(N_STEPS*(float)BATCH));
}

extern "C" void kernel_launch(void* const* d_in, const int* in_sizes, int n_in,
                              void* d_out, int out_size, void* d_ws, size_t ws_size,
                              hipStream_t stream){
  const void* x         = d_in[0];
  const void* bemv      = d_in[1];
  const void* gmat      = d_in[2];
  const void* bn_w      = d_in[3];
  const void* bn_b      = d_in[4];
  const void* init_fc0  = d_in[5];
  const void* init_bnw0 = d_in[6];
  const void* init_bnb0 = d_in[7];
  const void* init_fc1  = d_in[8];
  const void* init_bnw1 = d_in[9];
  const void* init_bnb1 = d_in[10];
  const void* step_fc0  = d_in[11];
  const void* step_bnw0 = d_in[12];
  const void* step_bnb0 = d_in[13];
  const void* step_fc1  = d_in[14];
  const void* step_bnw1 = d_in[15];
  const void* step_bnb1 = d_in[16];
  const void* att_fc    = d_in[17];
  const void* att_bnw   = d_in[18];
  const void* att_bnb   = d_in[19];
  const void* sa_in_w   = d_in[20];
  const void* sa_in_b   = d_in[21];
  const void* sa_out_w  = d_in[22];
  const void* sa_out_b  = d_in[23];

  float* out       = (float*)d_out;
  float* steps_out = out;                                  // 3*1024*64 f32
  float* mloss_out = out + (size_t)N_STEPS*BATCH*N_D;      // 1 f32
  float* amaps     = mloss_out + 1;                        // 3*1024*256*256 f32

  float* w     = (float*)d_ws;
  float* mean  = w;                  // 256
  float* istd  = w + 256;            // 256
  float* flag  = w + 512;            // 1 (+pad)
  float* lrow  = w + 1024;           // 3072
  float* sa    = w + 4096;           // 2048
  float* sbuf  = sa + 2048;          // 2048
  float* xn    = sbuf + 2048;        // 262144
  float* H     = xn   + 262144;      // 262144
  float* G0    = H    + 262144;      // 131072
  float* att   = G0   + 131072;      // 65536
  float* tab   = att  + 65536;       // 262144
  float* prior = tab  + 262144;      // 262144
  float* y     = prior + 262144;     // 262144

  dim3 gemmGrid(8, 32);
  dim3 gluGrid(4, 8);
  dim3 gstGrid(8, 8);

  detect_k<<<1, 256, 0, stream>>>((const unsigned short*)x, flag);
  bnstats_k<<<256, 256, 0, stream>>>(x, mean, istd, flag);
  xn_k<<<1024, 256, 0, stream>>>(x, mean, istd, bn_w, bn_b, xn, flag);

  // initial feature transformer on [xn | bemv]
  gemm_bt_k<<<gemmGrid, 256, 0, stream>>>(xn, bemv, 256, init_fc0, 0, H, 512, flag);
  gbnglu_k<0><<<gluGrid, 256, 0, stream>>>(H, init_bnw0, init_bnb0, 0, nullptr, G0, nullptr, nullptr, flag);
  gemm_bt_k<<<gemmGrid, 256, 0, stream>>>(G0, nullptr, 128, init_fc1, 0, H, 128, flag);
  gbnglu_k<1><<<gluGrid, 256, 0, stream>>>(H, init_bnw1, init_bnb1, 0, G0, nullptr, att, nullptr, flag);

  for (int s = 0; s < N_STEPS; ++s){
    // a = GBN(att @ att_fc[s]^T)
    gemm_bt_k<<<gemmGrid, 256, 0, stream>>>(att, nullptr, 64, att_fc, (size_t)s*AD*N_A, H, 64, flag);
    gstats_k<<<gstGrid, 256, 0, stream>>>(H, att_bnw, att_bnb, (size_t)s*256, sa, sbuf, flag);
    // sparsemax (wave-per-row) + prior + loss partials
    spmax_k<<<256, 256, 0, stream>>>(H, sa, sbuf, prior, tab, lrow + s*1024, s == 0);
    // fused x_masked + self-attn + amap
    attn_k<<<1024, 256, 0, stream>>>(tab, gmat, xn, y, sa_in_w, sa_in_b, sa_out_w, sa_out_b, s, amaps, flag);
    // step feature transformer on [y | bemv]
    gemm_bt_k<<<gemmGrid, 256, 0, stream>>>(y, bemv, 256, step_fc0, (size_t)s*256*512, H, 512, flag);
    gbnglu_k<0><<<gluGrid, 256, 0, stream>>>(H, step_bnw0, step_bnb0, (size_t)s*256, nullptr, G0, nullptr, nullptr, flag);
    gemm_bt_k<<<gemmGrid, 256, 0, stream>>>(G0, nullptr, 128, step_fc1, (size_t)s*256*128, H, 128, flag);
    gbnglu_k<1><<<gluGrid, 256, 0, stream>>>(H, step_bnw1, step_bnb1, (size_t)s*256, G0, nullptr, att,
                                             steps_out + (size_t)s*BATCH*N_D, flag);
  }
  mloss_k<<<1, 256, 0, stream>>>(lrow, mloss_out);
}

// Round 6
// 440.368 us; speedup vs baseline: 2.2238x; 1.0193x over previous
//
#include <hip/hip_runtime.h>
#include <hip/hip_bf16.h>

#define BATCH 1024
#define F_IN 256
#define N_D 64
#define N_A 64
#define VBS 128
#define N_STEPS 3
#define FO 128
#define D_CAT 512
#define AD 256
#define GAMMA_C 1.3f
#define BN_EPS_C 1e-5f
#define SQRT_HALF_C 0.70710678118654752440f

// ---- input loader: f32 or bf16 decided at runtime by detector flag --------
__device__ __forceinline__ float ldin(const void* p, size_t i, int isbf){
  if (isbf) return __bfloat162float(((const __hip_bfloat16*)p)[i]);
  return ((const float*)p)[i];
}
__device__ __forceinline__ float4 ld4(const void* p, size_t i, int isbf){
  if (!isbf) return *(const float4*)((const float*)p + i);
  const __hip_bfloat16* q = (const __hip_bfloat16*)p + i;
  return make_float4(__bfloat162float(q[0]), __bfloat162float(q[1]),
                     __bfloat162float(q[2]), __bfloat162float(q[3]));
}

// ---- wave (64-lane) butterfly reductions: result in ALL lanes -------------
__device__ __forceinline__ float wsum(float v){
#pragma unroll
  for (int o = 32; o > 0; o >>= 1) v += __shfl_xor(v, o);
  return v;
}
__device__ __forceinline__ float wmaxr(float v){
#pragma unroll
  for (int o = 32; o > 0; o >>= 1) v = fmaxf(v, __shfl_xor(v, o));
  return v;
}
__device__ __forceinline__ float wminr(float v){
#pragma unroll
  for (int o = 32; o > 0; o >>= 1) v = fminf(v, __shfl_xor(v, o));
  return v;
}
__device__ __forceinline__ float block_sum(float v, float* sb){
  int t = threadIdx.x;
  sb[t] = v; __syncthreads();
#pragma unroll
  for (int s = 128; s > 0; s >>= 1){
    if (t < s) sb[t] += sb[t + s];
    __syncthreads();
  }
  float r = sb[0]; __syncthreads();
  return r;
}

// ---- dtype detector (even uint16s: f32 mantissa=uniform, bf16=narrow exp) -
__global__ void detect_k(const unsigned short* __restrict__ u, float* __restrict__ flag){
  __shared__ int cnt;
  if (threadIdx.x == 0) cnt = 0;
  __syncthreads();
  int c = 0;
  for (int j = 0; j < 16; ++j){
    unsigned short v = u[(size_t)(threadIdx.x * 16 + j) * 2];
    int e = (v >> 7) & 0xFF;
    if (e >= 118 && e <= 134) c++;
  }
  atomicAdd(&cnt, c);
  __syncthreads();
  if (threadIdx.x == 0) flag[0] = (cnt > 2048) ? 1.0f : 0.0f;
}

// ---- full-batch BN stats (one block per feature) ---------------------------
__global__ void bnstats_k(const void* __restrict__ x, float* __restrict__ mean,
                          float* __restrict__ istd, const float* __restrict__ flg){
  __shared__ float sb[256];
  const int isbf = flg[0] != 0.0f;
  int f = blockIdx.x, t = threadIdx.x;
  float s = 0.f, ss = 0.f;
  for (int r = t; r < BATCH; r += 256){
    float v = ldin(x, (size_t)r * F_IN + f, isbf);
    s += v; ss += v * v;
  }
  s  = block_sum(s, sb);
  ss = block_sum(ss, sb);
  if (t == 0){
    float m = s * (1.f / BATCH);
    mean[f] = m;
    istd[f] = rsqrtf(ss * (1.f / BATCH) - m * m + BN_EPS_C);
  }
}

__global__ void xn_k(const void* __restrict__ x, const float* __restrict__ mean,
                     const float* __restrict__ istd, const void* __restrict__ bw,
                     const void* __restrict__ bb, float* __restrict__ xn,
                     const float* __restrict__ flg){
  const int isbf = flg[0] != 0.0f;
  int idx = blockIdx.x * 256 + threadIdx.x;
  int f = idx & (F_IN - 1);
  xn[idx] = (ldin(x, idx, isbf) - mean[f]) * istd[f] * ldin(bw, f, isbf) + ldin(bb, f, isbf);
}

// ---- GEMM (BT): C(1024x256) = A(1024xK) @ W^T, W (256,K) row-major --------
__global__ __launch_bounds__(256)
void gemm_bt_k(const float* __restrict__ A1, const void* __restrict__ A2, int split,
               const void* __restrict__ W, size_t woff, float* __restrict__ C,
               int K, const float* __restrict__ flg){
  __shared__ float As[32][34];
  __shared__ float Ws[32][34];
  const int isbf = flg[0] != 0.0f;
  const int n0 = blockIdx.x * 32, m0 = blockIdx.y * 32;
  const int t = threadIdx.x;
  const int tx = t & 15, ty = t >> 4;
  const int lr = t >> 3, lk = (t & 7) * 4;
  const int nc = K >> 5;
  float a00 = 0.f, a01 = 0.f, a10 = 0.f, a11 = 0.f;

  auto lda = [&](int k0) -> float4 {
    int gk = k0 + lk, gr = m0 + lr;
    if (gk < split) return *(const float4*)(A1 + (size_t)gr * split + gk);
    return ld4(A2, (size_t)gr * (K - split) + (gk - split), isbf);
  };
  auto ldw = [&](int k0) -> float4 {
    return ld4(W, woff + (size_t)(n0 + lr) * K + k0 + lk, isbf);
  };

  float4 ra = lda(0), rw = ldw(0);
  for (int c = 0; c < nc; ++c){
    As[lk+0][lr] = ra.x; As[lk+1][lr] = ra.y; As[lk+2][lr] = ra.z; As[lk+3][lr] = ra.w;
    Ws[lk+0][lr] = rw.x; Ws[lk+1][lr] = rw.y; Ws[lk+2][lr] = rw.z; Ws[lk+3][lr] = rw.w;
    __syncthreads();
    float4 na = ra, nw = rw;
    if (c + 1 < nc){ na = lda((c+1) << 5); nw = ldw((c+1) << 5); }
#pragma unroll
    for (int kk = 0; kk < 32; ++kk){
      float2 av = *(const float2*)&As[kk][ty*2];
      float2 wv = *(const float2*)&Ws[kk][tx*2];
      a00 += av.x * wv.x; a01 += av.x * wv.y;
      a10 += av.y * wv.x; a11 += av.y * wv.y;
    }
    __syncthreads();
    ra = na; rw = nw;
  }
  int r0 = m0 + ty*2, c0 = n0 + tx*2;
  float* Cp = C + (size_t)r0 * 256 + c0;
  Cp[0] = a00; Cp[1] = a01; Cp[256] = a10; Cp[257] = a11;
}

// ---- GEMM with fused GLU A-operand: C = glu(H1;aff) @ W^T, K=128 ----------
__global__ __launch_bounds__(256)
void gemm_glu_k(const float* __restrict__ H1, const float* __restrict__ saf,
                const float* __restrict__ sbf, const void* __restrict__ W,
                size_t woff, float* __restrict__ C, const float* __restrict__ flg){
  __shared__ float As[32][34];
  __shared__ float Ws[32][34];
  const int isbf = flg[0] != 0.0f;
  const int n0 = blockIdx.x * 32, m0 = blockIdx.y * 32;
  const int t = threadIdx.x;
  const int tx = t & 15, ty = t >> 4;
  const int lr = t >> 3, lk = (t & 7) * 4;
  float a00 = 0.f, a01 = 0.f, a10 = 0.f, a11 = 0.f;

  auto lda = [&](int k0) -> float4 {
    int gk = k0 + lk, gr = m0 + lr, g = gr >> 7;
    float4 h0 = *(const float4*)(H1 + (size_t)gr*256 + gk);
    float4 h1 = *(const float4*)(H1 + (size_t)gr*256 + gk + 128);
    float4 A0 = *(const float4*)(saf + g*256 + gk);
    float4 B0 = *(const float4*)(sbf + g*256 + gk);
    float4 A1 = *(const float4*)(saf + g*256 + gk + 128);
    float4 B1 = *(const float4*)(sbf + g*256 + gk + 128);
    float4 r;
    r.x = (h0.x*A0.x + B0.x) / (1.f + __expf(-(h1.x*A1.x + B1.x)));
    r.y = (h0.y*A0.y + B0.y) / (1.f + __expf(-(h1.y*A1.y + B1.y)));
    r.z = (h0.z*A0.z + B0.z) / (1.f + __expf(-(h1.z*A1.z + B1.z)));
    r.w = (h0.w*A0.w + B0.w) / (1.f + __expf(-(h1.w*A1.w + B1.w)));
    return r;
  };
  auto ldw = [&](int k0) -> float4 {
    return ld4(W, woff + (size_t)(n0 + lr) * 128 + k0 + lk, isbf);
  };

  float4 ra = lda(0), rw = ldw(0);
#pragma unroll 1
  for (int c = 0; c < 4; ++c){
    As[lk+0][lr] = ra.x; As[lk+1][lr] = ra.y; As[lk+2][lr] = ra.z; As[lk+3][lr] = ra.w;
    Ws[lk+0][lr] = rw.x; Ws[lk+1][lr] = rw.y; Ws[lk+2][lr] = rw.z; Ws[lk+3][lr] = rw.w;
    __syncthreads();
    float4 na = ra, nw = rw;
    if (c + 1 < 4){ na = lda((c+1) << 5); nw = ldw((c+1) << 5); }
#pragma unroll
    for (int kk = 0; kk < 32; ++kk){
      float2 av = *(const float2*)&As[kk][ty*2];
      float2 wv = *(const float2*)&Ws[kk][tx*2];
      a00 += av.x * wv.x; a01 += av.x * wv.y;
      a10 += av.y * wv.x; a11 += av.y * wv.y;
    }
    __syncthreads();
    ra = na; rw = nw;
  }
  int r0 = m0 + ty*2, c0 = n0 + tx*2;
  float* Cp = C + (size_t)r0 * 256 + c0;
  Cp[0] = a00; Cp[1] = a01; Cp[256] = a10; Cp[257] = a11;
}

// ---- ghost-BN stats -> per-(group,col) affine (a = istd*w, b2 = b - m*a) --
__global__ __launch_bounds__(256)
void gstats_k(const float* __restrict__ H, const void* __restrict__ w,
              const void* __restrict__ b, size_t off, float* __restrict__ sa,
              float* __restrict__ sb, const float* __restrict__ flg){
  __shared__ float ps[8][32], pss[8][32];
  const int isbf = flg[0] != 0.0f;
  int c0 = blockIdx.x * 32, g = blockIdx.y;
  int tx = threadIdx.x & 31, q = threadIdx.x >> 5;
  const float* Hp = H + ((size_t)g*128 + q*16) * 256 + c0 + tx;
  float s = 0.f, ss = 0.f;
#pragma unroll
  for (int i = 0; i < 16; ++i){ float v = Hp[(size_t)i*256]; s += v; ss += v*v; }
  ps[q][tx] = s; pss[q][tx] = ss;
  __syncthreads();
  if (threadIdx.x < 32){
    int t = threadIdx.x, col = c0 + t;
    float S = 0.f, SS = 0.f;
#pragma unroll
    for (int qq = 0; qq < 8; ++qq){ S += ps[qq][t]; SS += pss[qq][t]; }
    float m = S * (1.f/128), is = rsqrtf(SS * (1.f/128) - m*m + BN_EPS_C);
    float wv = ldin(w, off + col, isbf), bv = ldin(b, off + col, isbf);
    float A = is * wv;
    sa[g*256 + col] = A;
    sb[g*256 + col] = bv - m * A;
  }
}

// ---- fused sparsemax + prior + loss + sparse xm GEMM ----------------------
__global__ __launch_bounds__(256)
void spmaxxm_k(const float* __restrict__ H, const float* __restrict__ sa,
               const float* __restrict__ sb, float* __restrict__ prior,
               const float* __restrict__ xn, const void* __restrict__ gmat,
               float* __restrict__ xm, float* __restrict__ lrow,
               int first, const float* __restrict__ flg){
  __shared__ __align__(16) float tabs[4][256];
  __shared__ unsigned int msk[4][2];
  const int isbf = flg[0] != 0.0f;
  int lane = threadIdx.x & 63, wv = threadIdx.x >> 6;
  int b0 = blockIdx.x * 4;
  int b = b0 + wv, g = b >> 7;
  size_t rb = (size_t)b * 256;
  int j0 = lane * 4;
  float4 h4 = *(const float4*)(H + rb + j0);
  float4 A4 = *(const float4*)(sa + (size_t)g*256 + j0);
  float4 B4 = *(const float4*)(sb + (size_t)g*256 + j0);
  float pr[4];
  if (first){ pr[0] = pr[1] = pr[2] = pr[3] = 1.f; }
  else { float4 p4 = *(const float4*)(prior + rb + j0); pr[0]=p4.x; pr[1]=p4.y; pr[2]=p4.z; pr[3]=p4.w; }
  float z[4];
  z[0] = (h4.x*A4.x + B4.x) * pr[0];
  z[1] = (h4.y*A4.y + B4.y) * pr[1];
  z[2] = (h4.z*A4.z + B4.z) * pr[2];
  z[3] = (h4.w*A4.w + B4.w) * pr[3];
  float zm = wmaxr(fmaxf(fmaxf(z[0], z[1]), fmaxf(z[2], z[3])));
  float lo = zm - 1.f, hi = zm;
#pragma unroll 1
  for (int it = 0; it < 30; ++it){
    float mid = 0.5f * (lo + hi);
    float s = 0.f;
#pragma unroll
    for (int e = 0; e < 4; ++e){ float d = z[e] - mid; s += d > 0.f ? d : 0.f; }
    s = wsum(s);
    if (s >= 1.f) lo = mid; else hi = mid;
  }
  float tau = 0.5f * (lo + hi);
  float p[4], ls = 0.f;
#pragma unroll
  for (int e = 0; e < 4; ++e){
    p[e] = z[e] - tau; p[e] = p[e] > 0.f ? p[e] : 0.f;
    ls += p[e] * __logf(p[e] + 1e-15f);
  }
  *(float4*)&tabs[wv][j0] = make_float4(p[0], p[1], p[2], p[3]);
  *(float4*)(prior + rb + j0) = make_float4(pr[0]*(GAMMA_C - p[0]), pr[1]*(GAMMA_C - p[1]),
                                            pr[2]*(GAMMA_C - p[2]), pr[3]*(GAMMA_C - p[3]));
  ls = wsum(ls);
  if (lane == 0) lrow[b] = ls;
  bool nz = (p[0] > 0.f) | (p[1] > 0.f) | (p[2] > 0.f) | (p[3] > 0.f);
  unsigned long long bm = __ballot(nz);
  if (lane == 0){ msk[wv][0] = (unsigned int)bm; msk[wv][1] = (unsigned int)(bm >> 32); }
  __syncthreads();
  // phase 2: thread t = col t; sparse chunk skip via uniform masks
  int t = threadIdx.x;
  unsigned long long M0 = msk[0][0] | ((unsigned long long)msk[0][1] << 32);
  unsigned long long M1 = msk[1][0] | ((unsigned long long)msk[1][1] << 32);
  unsigned long long M2 = msk[2][0] | ((unsigned long long)msk[2][1] << 32);
  unsigned long long M3 = msk[3][0] | ((unsigned long long)msk[3][1] << 32);
  float a0 = 0.f, a1 = 0.f, a2 = 0.f, a3 = 0.f;
#pragma unroll 1
  for (int c = 0; c < 64; ++c){
    int r0a = (int)((M0 >> c) & 1), r1a = (int)((M1 >> c) & 1);
    int r2a = (int)((M2 >> c) & 1), r3a = (int)((M3 >> c) & 1);
    if (r0a | r1a | r2a | r3a){
      int k = c * 4;
      float g0 = ldin(gmat, (size_t)(k+0)*256 + t, isbf);
      float g1 = ldin(gmat, (size_t)(k+1)*256 + t, isbf);
      float g2 = ldin(gmat, (size_t)(k+2)*256 + t, isbf);
      float g3 = ldin(gmat, (size_t)(k+3)*256 + t, isbf);
      if (r0a){ float4 tv = *(float4*)&tabs[0][k]; a0 += tv.x*g0 + tv.y*g1 + tv.z*g2 + tv.w*g3; }
      if (r1a){ float4 tv = *(float4*)&tabs[1][k]; a1 += tv.x*g0 + tv.y*g1 + tv.z*g2 + tv.w*g3; }
      if (r2a){ float4 tv = *(float4*)&tabs[2][k]; a2 += tv.x*g0 + tv.y*g1 + tv.z*g2 + tv.w*g3; }
      if (r3a){ float4 tv = *(float4*)&tabs[3][k]; a3 += tv.x*g0 + tv.y*g1 + tv.z*g2 + tv.w*g3; }
    }
  }
  xm[(size_t)(b0+0)*256 + t] = a0 * xn[(size_t)(b0+0)*256 + t];
  xm[(size_t)(b0+1)*256 + t] = a1 * xn[(size_t)(b0+1)*256 + t];
  xm[(size_t)(b0+2)*256 + t] = a2 * xn[(size_t)(b0+2)*256 + t];
  xm[(size_t)(b0+3)*256 + t] = a3 * xn[(size_t)(b0+3)*256 + t];
}

// ---- 1D self-attention + amap write (winning round-4 structure) -----------
__global__ __launch_bounds__(256)
void attn_k(const float* __restrict__ xm, float* __restrict__ y,
            const void* __restrict__ in_w, const void* __restrict__ in_b,
            const void* __restrict__ out_w, const void* __restrict__ out_b,
            int s, float* __restrict__ amap, const float* __restrict__ flg){
  __shared__ __align__(16) float qs[256], ks[256], vs[256], ms[256], rz[256];
  __shared__ float r1[4], r2[4];
  const int isbf = flg[0] != 0.0f;
  int b = blockIdx.x, t = threadIdx.x;
  float w0 = ldin(in_w, s*3+0, isbf), w1 = ldin(in_w, s*3+1, isbf), w2 = ldin(in_w, s*3+2, isbf);
  float b0 = ldin(in_b, s*3+0, isbf), b1 = ldin(in_b, s*3+1, isbf), b2 = ldin(in_b, s*3+2, isbf);
  float ow = ldin(out_w, s, isbf), ob = ldin(out_b, s, isbf);
  float xv = xm[(size_t)b*256 + t];
  float q = xv*w0 + b0, k = xv*w1 + b1, v = xv*w2 + b2;
  qs[t] = q; ks[t] = k; vs[t] = v;
  int lane = t & 63, wv = t >> 6;
  float km = wmaxr(k), kn = wminr(k);
  if (lane == 0){ r1[wv] = km; r2[wv] = kn; }
  __syncthreads();
  float kmax = fmaxf(fmaxf(r1[0], r1[1]), fmaxf(r1[2], r1[3]));
  float kmin = fminf(fminf(r2[0], r2[1]), fminf(r2[2], r2[3]));
  // pass A: thread t owns row i=t; closed-form row max
  float mi = (q >= 0.f) ? q*kmax : q*kmin;
  float Z = 0.f, Y = 0.f;
#pragma unroll 8
  for (int j = 0; j < 256; j += 4){
    float4 k4 = *(const float4*)&ks[j];
    float4 v4 = *(const float4*)&vs[j];
    float e0 = __expf(q*k4.x - mi), e1 = __expf(q*k4.y - mi);
    float e2 = __expf(q*k4.z - mi), e3 = __expf(q*k4.w - mi);
    Z += (e0 + e1) + (e2 + e3);
    Y += (e0*v4.x + e1*v4.y) + (e2*v4.z + e3*v4.w);
  }
  float rzv = 1.f / Z;
  y[(size_t)b*256 + t] = Y*rzv*ow + ob;
  ms[t] = mi; rz[t] = rzv;
  __syncthreads();
  // pass B: thread t owns 2 adjacent cols x 128 rows; float2 temporal stores
  int c0 = (t & 127) * 2;
  int rh = (t >> 7) * 128;
  float k0 = ks[c0], k1 = ks[c0 + 1];
  size_t base = ((size_t)s*BATCH + b) * 65536 + c0;
#pragma unroll 8
  for (int i = 0; i < 128; i += 4){
    int r = rh + i;
    float4 q4 = *(const float4*)&qs[r];
    float4 m4 = *(const float4*)&ms[r];
    float4 s4 = *(const float4*)&rz[r];
    float e00 = __expf(q4.x*k0 - m4.x) * s4.x, e01 = __expf(q4.x*k1 - m4.x) * s4.x;
    float e10 = __expf(q4.y*k0 - m4.y) * s4.y, e11 = __expf(q4.y*k1 - m4.y) * s4.y;
    float e20 = __expf(q4.z*k0 - m4.z) * s4.z, e21 = __expf(q4.z*k1 - m4.z) * s4.z;
    float e30 = __expf(q4.w*k0 - m4.w) * s4.w, e31 = __expf(q4.w*k1 - m4.w) * s4.w;
    *(float2*)(amap + base + (size_t)(r+0)*256) = make_float2(e00, e01);
    *(float2*)(amap + base + (size_t)(r+1)*256) = make_float2(e10, e11);
    *(float2*)(amap + base + (size_t)(r+2)*256) = make_float2(e20, e21);
    *(float2*)(amap + base + (size_t)(r+3)*256) = make_float2(e30, e31);
  }
}

// ---- parallel combine: f = (glu0(H1) + glu1(H2))*sqrt_half ----------------
__global__ __launch_bounds__(256)
void combine_k(const float* __restrict__ H1, const float* __restrict__ sa0,
               const float* __restrict__ sb0, const float* __restrict__ H2,
               const float* __restrict__ sa1, const float* __restrict__ sb1,
               float* __restrict__ att, float* __restrict__ steps_out){
  int r = blockIdx.x * 2 + (threadIdx.x >> 7);
  int j = threadIdx.x & 127;
  int g = r >> 7;
  float h0 = H1[(size_t)r*256 + j],  h1 = H1[(size_t)r*256 + j + 128];
  float n0 = h0 * sa0[g*256 + j]     + sb0[g*256 + j];
  float n1 = h1 * sa0[g*256 + j+128] + sb0[g*256 + j+128];
  float g0 = n0 / (1.f + __expf(-n1));
  float h2 = H2[(size_t)r*256 + j],  h3 = H2[(size_t)r*256 + j + 128];
  float m0 = h2 * sa1[g*256 + j]     + sb1[g*256 + j];
  float m1 = h3 * sa1[g*256 + j+128] + sb1[g*256 + j+128];
  float g1 = m0 / (1.f + __expf(-m1));
  float f = (g0 + g1) * SQRT_HALF_C;
  if (j < 64){
    if (steps_out) steps_out[(size_t)r*64 + j] = f > 0.f ? f : 0.01f*f;
  } else {
    att[(size_t)r*64 + (j - 64)] = f;
  }
}

// ---- final m_loss ----------------------------------------------------------
__global__ void mloss_k(const float* __restrict__ lrow, float* __restrict__ outp){
  __shared__ float sb[256];
  int t = threadIdx.x;
  float s = 0.f;
  for (int i = t; i < N_STEPS*BATCH; i += 256) s += lrow[i];
  s = block_sum(s, sb);
  if (t == 0) outp[0] = s * (1.f/(N_STEPS*(float)BATCH));
}

extern "C" void kernel_launch(void* const* d_in, const int* in_sizes, int n_in,
                              void* d_out, int out_size, void* d_ws, size_t ws_size,
                              hipStream_t stream){
  const void* x         = d_in[0];
  const void* bemv      = d_in[1];
  const void* gmat      = d_in[2];
  const void* bn_w      = d_in[3];
  const void* bn_b      = d_in[4];
  const void* init_fc0  = d_in[5];
  const void* init_bnw0 = d_in[6];
  const void* init_bnb0 = d_in[7];
  const void* init_fc1  = d_in[8];
  const void* init_bnw1 = d_in[9];
  const void* init_bnb1 = d_in[10];
  const void* step_fc0  = d_in[11];
  const void* step_bnw0 = d_in[12];
  const void* step_bnb0 = d_in[13];
  const void* step_fc1  = d_in[14];
  const void* step_bnw1 = d_in[15];
  const void* step_bnb1 = d_in[16];
  const void* att_fc    = d_in[17];
  const void* att_bnw   = d_in[18];
  const void* att_bnb   = d_in[19];
  const void* sa_in_w   = d_in[20];
  const void* sa_in_b   = d_in[21];
  const void* sa_out_w  = d_in[22];
  const void* sa_out_b  = d_in[23];

  float* out       = (float*)d_out;
  float* steps_out = out;                                  // 3*1024*64 f32
  float* mloss_out = out + (size_t)N_STEPS*BATCH*N_D;      // 1 f32
  float* amaps     = mloss_out + 1;                        // 3*1024*256*256 f32

  float* w     = (float*)d_ws;
  float* flag  = w;                  // 1 (+pad)
  float* mean  = w + 16;             // 256
  float* istd  = w + 272;            // 256
  float* lrow  = w + 528;            // 3072 (-> 3600)
  float* sa0   = w + 4096;           // 2048
  float* sb0   = sa0 + 2048;         // 2048
  float* sa1   = sb0 + 2048;         // 2048
  float* sb1   = sa1 + 2048;         // 2048
  float* saA   = sb1 + 2048;         // 2048
  float* sbA   = saA + 2048;         // 2048 (-> 16384)
  float* xn    = w + 16384;          // 262144
  float* H1    = xn   + 262144;      // 262144
  float* H2    = H1   + 262144;      // 262144
  float* att   = H2   + 262144;      // 65536
  float* xm    = att  + 65536;       // 262144
  float* prior = xm   + 262144;      // 262144
  float* y     = prior + 262144;     // 262144

  dim3 gemmGrid(8, 32);
  dim3 gstGrid(8, 8);

  detect_k<<<1, 256, 0, stream>>>((const unsigned short*)x, flag);
  bnstats_k<<<256, 256, 0, stream>>>(x, mean, istd, flag);
  xn_k<<<1024, 256, 0, stream>>>(x, mean, istd, bn_w, bn_b, xn, flag);

  // initial feature transformer on [xn | bemv]
  gemm_bt_k<<<gemmGrid, 256, 0, stream>>>(xn, bemv, 256, init_fc0, 0, H1, 512, flag);
  gstats_k<<<gstGrid, 256, 0, stream>>>(H1, init_bnw0, init_bnb0, 0, sa0, sb0, flag);
  gemm_glu_k<<<gemmGrid, 256, 0, stream>>>(H1, sa0, sb0, init_fc1, 0, H2, flag);
  gstats_k<<<gstGrid, 256, 0, stream>>>(H2, init_bnw1, init_bnb1, 0, sa1, sb1, flag);
  combine_k<<<512, 256, 0, stream>>>(H1, sa0, sb0, H2, sa1, sb1, att, nullptr);

  for (int s = 0; s < N_STEPS; ++s){
    // a = GBN(att @ att_fc[s]^T); then sparsemax + prior + loss + sparse xm
    gemm_bt_k<<<gemmGrid, 256, 0, stream>>>(att, nullptr, 64, att_fc, (size_t)s*AD*N_A, H1, 64, flag);
    gstats_k<<<gstGrid, 256, 0, stream>>>(H1, att_bnw, att_bnb, (size_t)s*256, saA, sbA, flag);
    spmaxxm_k<<<256, 256, 0, stream>>>(H1, saA, sbA, prior, xn, gmat, xm, lrow + s*1024, s == 0, flag);
    // self-attn + amap
    attn_k<<<1024, 256, 0, stream>>>(xm, y, sa_in_w, sa_in_b, sa_out_w, sa_out_b, s, amaps, flag);
    // step feature transformer on [y | bemv]
    gemm_bt_k<<<gemmGrid, 256, 0, stream>>>(y, bemv, 256, step_fc0, (size_t)s*256*512, H1, 512, flag);
    gstats_k<<<gstGrid, 256, 0, stream>>>(H1, step_bnw0, step_bnb0, (size_t)s*256, sa0, sb0, flag);
    gemm_glu_k<<<gemmGrid, 256, 0, stream>>>(H1, sa0, sb0, step_fc1, (size_t)s*256*128, H2, flag);
    gstats_k<<<gstGrid, 256, 0, stream>>>(H2, step_bnw1, step_bnb1, (size_t)s*256, sa1, sb1, flag);
    combine_k<<<512, 256, 0, stream>>>(H1, sa0, sb0, H2, sa1, sb1, att,
                                       steps_out + (size_t)s*BATCH*N_D);
  }
  mloss_k<<<1, 256, 0, stream>>>(lrow, mloss_out);
}